// Round 5
// baseline (339.861 us; speedup 1.0000x reference)
//
#include <hip/hip_runtime.h>
#include <hip/hip_bf16.h>

// Capsule EM routing, fused, votes recomputed in registers each pass.
// B=32, H=W=8, I=32 -> N=2048 per b (n = site*32 + i), O=64, P=16, routings=3.
//
// Round-5: wave = (b, fixed i, 16 sites), lane = o. w[i][o][:] loaded once
// per wave (16 VGPRs). ZERO global atomics: 4-wave LDS-atomic reduce ->
// one streaming 2112-float partial per block -> per-b reduce+stats kernel
// (also computes the EM stats; no separate stats pass, no memset).
// Grid (32,32) = 1024 blocks = 4 blocks/CU, 16 waves/CU.

#define NB 32
#define NN 2048
#define NO 64
#define NP 16
#define EPSF 1e-7f

// per-(b,group) partial / per-b stats layout: [slot][o]
//   slots 0..15 = sum rr'*v, 16..31 = sum rr'*v^2, 32 = rps
// stats: 0..15 = mean, 16..31 = 0.5/var, 32 = zzb = log(o_act+eps)-sum log(sigma+eps)
#define SLOTS 33
#define PART (SLOTS * NO)     // 2112 floats
#define NGRP 32               // blocks per b

template <bool FIRST>
__global__ __launch_bounds__(256) void accum_kernel(
    const float* __restrict__ pose,    // [B][N][16]
    const float* __restrict__ act,     // [B][N]
    const float* __restrict__ wmat,    // [I=32][O=64][16]
    const float* __restrict__ stats,   // [B][33][64] (null if FIRST)
    float* __restrict__ partial)       // [B][NGRP][33][64]
{
    __shared__ float pose_s[16 * 4 * 16];  // 16 sites x 4 i x 16 = 4 KB
    __shared__ float act_s[64];
    __shared__ float red[PART];            // 8.25 KB

    const int b   = blockIdx.y;
    const int gx  = blockIdx.x;   // 0..31
    const int sg  = gx >> 3;      // site-group 0..3 (16 sites each)
    const int iq  = gx & 7;       // i-quad 0..7
    const int tid = threadIdx.x;
    const int wv  = tid >> 6;     // wave -> i within quad
    const int o   = tid & 63;     // lane -> output capsule

    for (int j = tid; j < PART; j += 256) red[j] = 0.f;

    // stage pose tile: exactly one float4 per thread
    {
        const int s = tid >> 4, r = tid & 15, ic = r >> 2, wd = r & 3;
        const size_t g4 = ((size_t)b * NN + (sg * 16 + s) * 32 + iq * 4 + ic) * 4 + wd;
        ((float4*)pose_s)[tid] = ((const float4*)pose)[g4];
        if (tid < 64) {
            const int ss = tid >> 2, ii = tid & 3;
            act_s[tid] = act[(size_t)b * NN + (sg * 16 + ss) * 32 + iq * 4 + ii];
        }
    }

    // per-wave w: 16 registers, loaded once
    const int i = iq * 4 + wv;
    const float4* wp = (const float4*)(wmat + ((size_t)i * 64 + o) * 16);
    float4 w0 = wp[0], w1 = wp[1], w2 = wp[2], w3 = wp[3];

    float m[16], i2v[16], zzb = 0.f;
    if (!FIRST) {
        const float* st = stats + (size_t)b * PART;
        #pragma unroll
        for (int p = 0; p < 16; p++) m[p] = st[p * 64 + o];
        #pragma unroll
        for (int p = 0; p < 16; p++) i2v[p] = st[(16 + p) * 64 + o];
        zzb = st[32 * 64 + o];
    }

    float accR = 0.f, acc1[16], acc2[16];
    #pragma unroll
    for (int p = 0; p < 16; p++) { acc1[p] = 0.f; acc2[p] = 0.f; }

    __syncthreads();

    const float c1 = ((sg & 1) * 16 * 0 + 0.f);  // (placeholder removed below)
    for (int s = 0; s < 16; s++) {
        const int sp = sg * 16 + s;
        const float ch = ((sp >> 3) + 0.5f) * 0.125f;
        const float cw = ((sp & 7) + 0.5f) * 0.125f;
        const float4* pr4 = (const float4*)(pose_s + (s * 4 + wv) * 16);  // wave-uniform
        float v[16];
        #pragma unroll
        for (int a = 0; a < 4; a++) {
            float4 pa = pr4[a];
            v[a * 4 + 0] = pa.x * w0.x + pa.y * w1.x + pa.z * w2.x + pa.w * w3.x;
            v[a * 4 + 1] = pa.x * w0.y + pa.y * w1.y + pa.z * w2.y + pa.w * w3.y;
            v[a * 4 + 2] = pa.x * w0.z + pa.y * w1.z + pa.z * w2.z + pa.w * w3.z;
            v[a * 4 + 3] = pa.x * w0.w + pa.y * w1.w + pa.z * w2.w + pa.w * w3.w;
        }
        v[0] += ch;
        v[1] += cw;

        float rr;
        if (FIRST) {
            rr = 1.0f / 64.0f;
        } else {
            float d = zzb;
            #pragma unroll
            for (int p = 0; p < 16; p++) {
                float t = v[p] - m[p];
                d -= t * t * i2v[p];
            }
            float mx = d;
            #pragma unroll
            for (int sh = 32; sh > 0; sh >>= 1) mx = fmaxf(mx, __shfl_xor(mx, sh, 64));
            float e = __expf(d - mx);
            float sum = e;
            #pragma unroll
            for (int sh = 32; sh > 0; sh >>= 1) sum += __shfl_xor(sum, sh, 64);
            rr = e / sum;
        }
        float rp = rr * act_s[s * 4 + wv];
        accR += rp;
        #pragma unroll
        for (int p = 0; p < 16; p++) {
            float t = rp * v[p];
            acc1[p] += t;
            acc2[p] += t * v[p];
        }
    }

    // cross-wave reduce in LDS (4-way same-address max; cheap)
    atomicAdd(&red[32 * 64 + o], accR);
    #pragma unroll
    for (int p = 0; p < 16; p++) atomicAdd(&red[p * 64 + o], acc1[p]);
    #pragma unroll
    for (int p = 0; p < 16; p++) atomicAdd(&red[(16 + p) * 64 + o], acc2[p]);
    __syncthreads();

    float* dst = partial + ((size_t)b * NGRP + gx) * PART;
    for (int j = tid; j < PART; j += 256) dst[j] = red[j];
}

template <bool FINAL>
__global__ __launch_bounds__(256) void reduce_stats_kernel(
    const float* __restrict__ partial,  // [B][NGRP][33][64]
    const float* __restrict__ beta_v,   // [64]
    const float* __restrict__ beta_a,   // [64]
    float* __restrict__ stats_out,      // [B][33][64] (if !FINAL)
    float* __restrict__ out,            // poses+acts (if FINAL)
    float inv_temp)
{
    __shared__ float red[PART];
    const int b = blockIdx.x;
    const int tid = threadIdx.x;

    const float* pb = partial + (size_t)b * NGRP * PART;
    for (int j = tid; j < PART; j += 256) {
        float s = 0.f;
        #pragma unroll 4
        for (int g = 0; g < NGRP; g++) s += pb[(size_t)g * PART + j];
        red[j] = s;
    }
    __syncthreads();

    if (tid < 64) {
        const int o = tid;
        float rps = red[32 * 64 + o];
        float mm[16], var[16], logsum = 0.f;
        #pragma unroll
        for (int p = 0; p < 16; p++) {
            float s1 = red[p * 64 + o];
            float s2 = red[(16 + p) * 64 + o];
            float mv = s1 / rps;
            float vv = fmaxf(s2 / rps - mv * mv, 0.f);
            mm[p] = mv;
            var[p] = vv;
            logsum += __logf(sqrtf(vv) + EPSF);
        }
        float cost = rps * (16.0f * beta_v[o] + logsum);

        float cm = cost;
        #pragma unroll
        for (int sh = 32; sh > 0; sh >>= 1) cm += __shfl_xor(cm, sh, 64);
        cm *= (1.0f / 64.0f);
        float d = cost - cm;
        float cs = d * d;
        #pragma unroll
        for (int sh = 32; sh > 0; sh >>= 1) cs += __shfl_xor(cs, sh, 64);
        cs = sqrtf(cs * (1.0f / 64.0f));

        float x = inv_temp * (beta_a[o] + (cm - cost) / (cs + EPSF));
        float oa = 1.0f / (1.0f + __expf(-x));

        if (!FINAL) {
            float* st = stats_out + (size_t)b * PART;
            #pragma unroll
            for (int p = 0; p < 16; p++) st[p * 64 + o] = mm[p];
            #pragma unroll
            for (int p = 0; p < 16; p++) st[(16 + p) * 64 + o] = 0.5f / var[p];
            st[32 * 64 + o] = __logf(oa + EPSF) - logsum;
        } else {
            float* op = out + ((size_t)b * 64 + o) * 16;
            #pragma unroll
            for (int p = 0; p < 16; p++) op[p] = mm[p];
            out[(size_t)NB * NO * NP + (size_t)b * 64 + o] = oa;
        }
    }
}

extern "C" void kernel_launch(void* const* d_in, const int* in_sizes, int n_in,
                              void* d_out, int out_size, void* d_ws, size_t ws_size,
                              hipStream_t stream) {
    const float* pose   = (const float*)d_in[0];  // (32,8,8,32,4,4)
    const float* act    = (const float*)d_in[1];  // (32,8,8,32)
    const float* wmat   = (const float*)d_in[2];  // (32,64,4,4)
    const float* beta_v = (const float*)d_in[3];  // (1,64)
    const float* beta_a = (const float*)d_in[4];  // (1,64)
    float* out = (float*)d_out;
    float* ws = (float*)d_ws;

    float* part   = ws;                                   // 32*32*2112*4 = 8.65 MB
    float* stats0 = ws + (size_t)NB * NGRP * PART;        // 270 KB
    float* stats1 = stats0 + (size_t)NB * PART;           // 270 KB
    // every word is written before read -> no memset

    dim3 grid(NGRP, NB);  // 1024 blocks
    accum_kernel<true><<<grid, 256, 0, stream>>>(pose, act, wmat, nullptr, part);
    reduce_stats_kernel<false><<<NB, 256, 0, stream>>>(part, beta_v, beta_a, stats0, nullptr, 1.0f);
    accum_kernel<false><<<grid, 256, 0, stream>>>(pose, act, wmat, stats0, part);
    reduce_stats_kernel<false><<<NB, 256, 0, stream>>>(part, beta_v, beta_a, stats1, nullptr, 2.0f);
    accum_kernel<false><<<grid, 256, 0, stream>>>(pose, act, wmat, stats1, part);
    reduce_stats_kernel<true><<<NB, 256, 0, stream>>>(part, beta_v, beta_a, nullptr, out, 3.0f);
}

// Round 6
// 290.877 us; speedup vs baseline: 1.1684x; 1.1684x over previous
//
#include <hip/hip_runtime.h>
#include <hip/hip_bf16.h>

// Capsule EM routing, fused, votes recomputed in registers each pass.
// B=32, H=W=8, I=32 -> N=2048 per b (n = site*32 + i), O=64, P=16, routings=3.
//
// Round-6: diagnosis = VGPR-occupancy-capped (~2.5 waves/SIMD at default
// register allocation, grid-size invariant). Fix: __launch_bounds__(512,4)
// caps VGPRs at 128 -> 4 waves/SIMD. Inner loop is r3's proven form (per-item
// global w loads, scalar LDS broadcasts, max-subtracted softmax). Block = 8
// waves = 4 sites x 2 i-halves; grid (16,32) = 512 blocks, 2 blocks/CU.
// Tail: 8-wave LDS reduce -> 1 streaming partial/block -> 16 partials/b,
// so the per-b reduce+stats kernel reads only 135 KB/block.

#define NB 32
#define NN 2048
#define NO 64
#define NP 16
#define EPSF 1e-7f

#define BLK 512
#define GPB 16                // blocks per b
#define SPB 4                 // sites per block
#define SLOTS 33              // 0..15 sum rr'v, 16..31 sum rr'v^2, 32 rps
#define PART (SLOTS * NO)     // 2112 floats

// stats per b: [slot][o]: 0..15 mean, 16..31 = 0.5/var,
// 32 = zzb = log(o_act+eps) - sum_p log(sigma_p+eps)

template <bool FIRST>
__global__ __launch_bounds__(BLK, 4) void accum_kernel(
    const float* __restrict__ pose,    // [B][N][16]
    const float* __restrict__ act,     // [B][N]
    const float* __restrict__ wmat,    // [I=32][O=64][16]
    const float* __restrict__ stats,   // [B][33][64] (null if FIRST)
    float* __restrict__ partial)       // [B][GPB][33][64]
{
    __shared__ float pose_s[SPB * 32 * 16];  // 8 KB
    __shared__ float act_s[SPB * 32];
    __shared__ float red[PART];              // 8.25 KB

    const int b   = blockIdx.y;
    const int g   = blockIdx.x;   // 0..15
    const int tid = threadIdx.x;
    const int wv  = tid >> 6;     // 8 waves
    const int o   = tid & 63;     // lane = output capsule

    for (int j = tid; j < PART; j += BLK) red[j] = 0.f;
    {
        const float4* psrc = (const float4*)(pose + ((size_t)b * NN + g * (SPB * 32)) * 16);
        ((float4*)pose_s)[tid] = psrc[tid];  // exactly 512 float4
        if (tid < SPB * 32) act_s[tid] = act[(size_t)b * NN + g * (SPB * 32) + tid];
    }

    float m[16], i2v[16], zzb = 0.f;
    if (!FIRST) {
        const float* st = stats + (size_t)b * PART;
        #pragma unroll
        for (int p = 0; p < 16; p++) m[p] = st[p * 64 + o];
        #pragma unroll
        for (int p = 0; p < 16; p++) i2v[p] = st[(16 + p) * 64 + o];
        zzb = st[32 * 64 + o];
    }

    float accR = 0.f, acc1[16], acc2[16];
    #pragma unroll
    for (int p = 0; p < 16; p++) { acc1[p] = 0.f; acc2[p] = 0.f; }

    const int sl = wv >> 1;         // local site 0..3
    const int i0 = (wv & 1) * 16;   // i-half
    const int sp = g * SPB + sl;    // global site 0..63
    const float c0 = ((sp >> 3) + 0.5f) * 0.125f;
    const float c1 = ((sp & 7) + 0.5f) * 0.125f;

    __syncthreads();

    for (int ii = 0; ii < 16; ii++) {
        const int i = i0 + ii;
        const float4* wp = (const float4*)(wmat + ((size_t)i * 64 + o) * 16);
        float4 w0 = wp[0], w1 = wp[1], w2 = wp[2], w3 = wp[3];
        const int nl = sl * 32 + i;
        const float* pr = pose_s + nl * 16;  // wave-uniform -> broadcast
        float v[16];
        #pragma unroll
        for (int a = 0; a < 4; a++) {
            float pa0 = pr[a * 4 + 0], pa1 = pr[a * 4 + 1];
            float pa2 = pr[a * 4 + 2], pa3 = pr[a * 4 + 3];
            v[a * 4 + 0] = pa0 * w0.x + pa1 * w1.x + pa2 * w2.x + pa3 * w3.x;
            v[a * 4 + 1] = pa0 * w0.y + pa1 * w1.y + pa2 * w2.y + pa3 * w3.y;
            v[a * 4 + 2] = pa0 * w0.z + pa1 * w1.z + pa2 * w2.z + pa3 * w3.z;
            v[a * 4 + 3] = pa0 * w0.w + pa1 * w1.w + pa2 * w2.w + pa3 * w3.w;
        }
        v[0] += c0;
        v[1] += c1;

        float rr;
        if (FIRST) {
            rr = 1.0f / 64.0f;
        } else {
            float d = zzb;
            #pragma unroll
            for (int p = 0; p < 16; p++) {
                float t = v[p] - m[p];
                d -= t * t * i2v[p];
            }
            float mx = d;
            #pragma unroll
            for (int s = 32; s > 0; s >>= 1) mx = fmaxf(mx, __shfl_xor(mx, s, 64));
            float e = __expf(d - mx);
            float sum = e;
            #pragma unroll
            for (int s = 32; s > 0; s >>= 1) sum += __shfl_xor(sum, s, 64);
            rr = e / sum;
        }
        float rp = rr * act_s[nl];
        accR += rp;
        #pragma unroll
        for (int p = 0; p < 16; p++) {
            acc1[p] += rp * v[p];
            acc2[p] += rp * v[p] * v[p];
        }
    }

    // 8-wave LDS reduce (same-address within-wave none; across waves serialized
    // per address by HW -- 33 ops/wave, cheap)
    atomicAdd(&red[32 * 64 + o], accR);
    #pragma unroll
    for (int p = 0; p < 16; p++) atomicAdd(&red[p * 64 + o], acc1[p]);
    #pragma unroll
    for (int p = 0; p < 16; p++) atomicAdd(&red[(16 + p) * 64 + o], acc2[p]);
    __syncthreads();

    float* dst = partial + ((size_t)b * GPB + g) * PART;
    for (int j = tid; j < PART; j += BLK) dst[j] = red[j];
}

template <bool FINAL>
__global__ __launch_bounds__(256) void reduce_stats_kernel(
    const float* __restrict__ partial,  // [B][GPB][33][64]
    const float* __restrict__ beta_v,   // [64]
    const float* __restrict__ beta_a,   // [64]
    float* __restrict__ stats_out,      // [B][33][64] (if !FINAL)
    float* __restrict__ out,            // poses+acts (if FINAL)
    float inv_temp)
{
    __shared__ float red[PART];
    const int b = blockIdx.x;
    const int tid = threadIdx.x;

    const float* pb = partial + (size_t)b * GPB * PART;
    for (int j = tid; j < PART; j += 256) {
        float s = 0.f;
        #pragma unroll
        for (int g = 0; g < GPB; g++) s += pb[(size_t)g * PART + j];
        red[j] = s;
    }
    __syncthreads();

    if (tid < 64) {
        const int o = tid;
        float rps = red[32 * 64 + o];
        float mm[16], var[16], logsum = 0.f;
        #pragma unroll
        for (int p = 0; p < 16; p++) {
            float s1 = red[p * 64 + o];
            float s2 = red[(16 + p) * 64 + o];
            float mv = s1 / rps;
            float vv = fmaxf(s2 / rps - mv * mv, 0.f);
            mm[p] = mv;
            var[p] = vv;
            logsum += __logf(sqrtf(vv) + EPSF);
        }
        float cost = rps * (16.0f * beta_v[o] + logsum);

        float cm = cost;
        #pragma unroll
        for (int sh = 32; sh > 0; sh >>= 1) cm += __shfl_xor(cm, sh, 64);
        cm *= (1.0f / 64.0f);
        float d = cost - cm;
        float cs = d * d;
        #pragma unroll
        for (int sh = 32; sh > 0; sh >>= 1) cs += __shfl_xor(cs, sh, 64);
        cs = sqrtf(cs * (1.0f / 64.0f));

        float x = inv_temp * (beta_a[o] + (cm - cost) / (cs + EPSF));
        float oa = 1.0f / (1.0f + __expf(-x));

        if (!FINAL) {
            float* st = stats_out + (size_t)b * PART;
            #pragma unroll
            for (int p = 0; p < 16; p++) st[p * 64 + o] = mm[p];
            #pragma unroll
            for (int p = 0; p < 16; p++) st[(16 + p) * 64 + o] = 0.5f / var[p];
            st[32 * 64 + o] = __logf(oa + EPSF) - logsum;
        } else {
            float* op = out + ((size_t)b * 64 + o) * 16;
            #pragma unroll
            for (int p = 0; p < 16; p++) op[p] = mm[p];
            out[(size_t)NB * NO * NP + (size_t)b * 64 + o] = oa;
        }
    }
}

extern "C" void kernel_launch(void* const* d_in, const int* in_sizes, int n_in,
                              void* d_out, int out_size, void* d_ws, size_t ws_size,
                              hipStream_t stream) {
    const float* pose   = (const float*)d_in[0];  // (32,8,8,32,4,4)
    const float* act    = (const float*)d_in[1];  // (32,8,8,32)
    const float* wmat   = (const float*)d_in[2];  // (32,64,4,4)
    const float* beta_v = (const float*)d_in[3];  // (1,64)
    const float* beta_a = (const float*)d_in[4];  // (1,64)
    float* out = (float*)d_out;
    float* ws = (float*)d_ws;

    float* part   = ws;                               // 32*16*2112*4 = 4.33 MB
    float* stats0 = ws + (size_t)NB * GPB * PART;     // 270 KB
    float* stats1 = stats0 + (size_t)NB * PART;       // 270 KB
    // every word is written before read -> no memset

    dim3 grid(GPB, NB);  // 512 blocks x 512 threads
    accum_kernel<true><<<grid, BLK, 0, stream>>>(pose, act, wmat, nullptr, part);
    reduce_stats_kernel<false><<<NB, 256, 0, stream>>>(part, beta_v, beta_a, stats0, nullptr, 1.0f);
    accum_kernel<false><<<grid, BLK, 0, stream>>>(pose, act, wmat, stats0, part);
    reduce_stats_kernel<false><<<NB, 256, 0, stream>>>(part, beta_v, beta_a, stats1, nullptr, 2.0f);
    accum_kernel<false><<<grid, BLK, 0, stream>>>(pose, act, wmat, stats1, part);
    reduce_stats_kernel<true><<<NB, 256, 0, stream>>>(part, beta_v, beta_a, nullptr, out, 3.0f);
}